// Round 8
// baseline (180.656 us; speedup 1.0000x reference)
//
#include <hip/hip_runtime.h>
#include <math.h>

#define SRf 48000.0f
#define CSOUND 343.0f
#define RIR_LEN 24000
#define TAPS 81
#define HALFT 40
#define NB 8
#define NM 21                 // per-axis entries with order <= 10
#define NTRIP (NM * NM * NM)  // 9261 candidate triples
#define BLOCK 1024
#define MAXIMG 1600           // >= exact keeper count 1561

// 0.9^q for q = 0..10
__device__ __constant__ float c_beta[11] = {
    1.0f, 0.9f, 0.81f, 0.729f, 0.6561f, 0.59049f, 0.531441f,
    0.4782969f, 0.43046721f, 0.387420489f, 0.3486784401f};

// Per-axis image table restricted to order <= 10 (pure arithmetic, no LDS):
//   m in [0,10]:  p=0, n=m-5  -> sign=+1, off=2n, order=2|n|
//   m in [11,20]: p=1, n=m-15 -> sign=-1, off=2n, order=|n-1|+|n|
__device__ __forceinline__ void axis_entry(int m, float& sgn, float& off, int& ord) {
    if (m < 11) {
        int n = m - 5;
        sgn = 1.0f;
        off = 2.0f * (float)n;
        ord = 2 * abs(n);
    } else {
        int n = m - 15;
        sgn = -1.0f;
        off = 2.0f * (float)n;
        ord = abs(n - 1) + abs(n);
    }
}

// One block per batch: scan once, paint the whole private LDS RIR, write out.
// No workspace, no second kernel, no global atomics, no graph barrier.
__global__ __launch_bounds__(BLOCK) void rir_kernel(const float* __restrict__ x,
                                                    float* __restrict__ out) {
    __shared__ __align__(16) float s_tile[RIR_LEN];  // 96 KB private RIR
    __shared__ float4 s_e[MAXIMG];  // {amp, frac, amp*sin(pi*frac)/pi, i0}
    __shared__ int s_cnt;

    const float PIF = 3.14159265358979323846f;
    const int b = blockIdx.x;
    const int tid = threadIdx.x;

    const float* xb = x + b * 9;
    const float r0 = xb[0] * 10.0f, r1 = xb[1] * 10.0f, r2 = xb[2] * 10.0f;
    const float m0 = xb[3] * r0, m1 = xb[4] * r1, m2 = xb[5] * r2;
    const float s0 = xb[6] * r0, s1 = xb[7] * r1, s2 = xb[8] * r2;

    if (tid == 0) {
        s_cnt = 0;
        float d0 = m0 - s0, d1 = m1 - s1, d2 = m2 - s2;
        float dist = sqrtf(d0 * d0 + d1 * d1 + d2 * d2);
        out[NB * RIR_LEN + b] = 40.0f + SRf * dist / CSOUND;  // origin output
    }
    for (int j = tid * 4; j < RIR_LEN; j += BLOCK * 4)
        *(float4*)&s_tile[j] = make_float4(0.f, 0.f, 0.f, 0.f);
    __syncthreads();

    // ---- phase A: register-only scan of all candidates; compact keepers
    for (int r = tid; r < NTRIP; r += BLOCK) {
        int mi = r / (NM * NM);
        int rem = r - mi * (NM * NM);
        int mj = rem / NM;
        int mk = rem - mj * NM;

        float si, oi_; int qi; axis_entry(mi, si, oi_, qi);
        float sj, oj_; int qj; axis_entry(mj, sj, oj_, qj);
        float sk, ok_; int qk; axis_entry(mk, sk, ok_, qk);
        int q = qi + qj + qk;
        if (q > 10) continue;

        float dx = si * s0 + oi_ * r0 - m0;
        float dy = sj * s1 + oj_ * r1 - m1;
        float dz = sk * s2 + ok_ * r2 - m2;
        float dist = sqrtf(dx * dx + dy * dy + dz * dz);

        float tau = SRf * dist / CSOUND;
        float i0f = floorf(tau);
        int i0 = (int)i0f;
        if (i0 + HALFT + 1 >= RIR_LEN) continue;  // no in-range taps

        float fr = tau - i0f;
        float amp = c_beta[q] / (4.0f * PIF * dist);
        int slot = atomicAdd(&s_cnt, 1);
        float4 e;
        e.x = amp;
        e.y = fr;
        e.z = amp * __sinf(PIF * fr) * (1.0f / PIF);
        e.w = __int_as_float(i0);
        s_e[slot] = e;
    }
    __syncthreads();

    // ---- phase B: paint. Tap ki=0 is provably zero (|t|>40 unless frac==0,
    // and then sinc(-40)=0), so loop ki=1..80 with no window-support branch.
    const int n = s_cnt;
    const int total = n * (TAPS - 1);
    for (int w = tid; w < total; w += BLOCK) {
        int img = w / (TAPS - 1);
        int ki = w - img * (TAPS - 1) + 1;  // 1..80
        float4 e = s_e[img];
        int idx = __float_as_int(e.w) + HALFT + ki;
        if (idx >= RIR_LEN) continue;

        float tt = (float)(ki - HALFT) - e.y;           // in (-40, 40]
        float win = 0.5f * (1.0f + __cosf(PIF * (1.0f / 41.0f) * tt));
        float v = ((ki & 1) ? e.z : -e.z) * __builtin_amdgcn_rcpf(tt);
        v = (tt == 0.0f) ? e.x : v;                     // exact-integer delay case
        atomicAdd(&s_tile[idx], v * win);
    }
    __syncthreads();

    // ---- phase C: coalesced float4 writeout of the batch's RIR
    float* ob = out + (size_t)b * RIR_LEN;
    for (int j = tid * 4; j < RIR_LEN; j += BLOCK * 4)
        *(float4*)&ob[j] = *(const float4*)&s_tile[j];
}

extern "C" void kernel_launch(void* const* d_in, const int* in_sizes, int n_in,
                              void* d_out, int out_size, void* d_ws, size_t ws_size,
                              hipStream_t stream) {
    const float* x = (const float*)d_in[0];
    float* out = (float*)d_out;
    rir_kernel<<<NB, BLOCK, 0, stream>>>(x, out);
}

// Round 9
// 40.050 us; speedup vs baseline: 4.5108x; 4.5108x over previous
//
#include <hip/hip_runtime.h>
#include <math.h>

#define SRf 48000.0f
#define CSOUND 343.0f
#define RIR_LEN 24000
#define TAPS 81
#define HALFT 40
#define NB 8
#define NM 21                 // per-axis entries with order <= 10
#define NTRIP (NM * NM * NM)  // 9261 candidate triples
#define NSL 32                // image-slices per batch (r % NSL) -> 256 balanced blocks
#define BLOCK 1024
#define CAPS 192              // per-slice keeper capacity (mean ~49)

// 0.9^q for q = 0..10
__device__ __constant__ float c_beta[11] = {
    1.0f, 0.9f, 0.81f, 0.729f, 0.6561f, 0.59049f, 0.531441f,
    0.4782969f, 0.43046721f, 0.387420489f, 0.3486784401f};

// Per-axis image table restricted to order <= 10 (pure arithmetic):
//   m in [0,10]:  p=0, n=m-5  -> sign=+1, off=2n, order=2|n|
//   m in [11,20]: p=1, n=m-15 -> sign=-1, off=2n, order=|n-1|+|n|
__device__ __forceinline__ void axis_entry(int m, float& sgn, float& off, int& ord) {
    if (m < 11) {
        int n = m - 5;
        sgn = 1.0f;
        off = 2.0f * (float)n;
        ord = 2 * abs(n);
    } else {
        int n = m - 15;
        sgn = -1.0f;
        off = 2.0f * (float)n;
        ord = abs(n - 1) + abs(n);
    }
}

// Phase-ablatable paint kernel. mode: 0 = zero LDS + ws write;
// 1 = + candidate scan; 2 = + tap paint. Later phases runtime-skipped but
// statically reachable, so no phase is dead-code-eliminated.
__global__ __launch_bounds__(BLOCK) void k_paint(const float* __restrict__ x,
                                                 float* __restrict__ ws, int mode) {
    __shared__ __align__(16) float s_tile[RIR_LEN];  // 96 KB private partial RIR
    __shared__ float4 s_e[CAPS];  // {amp, frac, amp*sin(pi*frac)/pi, i0}
    __shared__ int s_cnt;

    const float PIF = 3.14159265358979323846f;
    const int b = blockIdx.x >> 5;
    const int sl = blockIdx.x & (NSL - 1);
    const int tid = threadIdx.x;

    const float* xb = x + b * 9;
    const float r0 = xb[0] * 10.0f, r1 = xb[1] * 10.0f, r2 = xb[2] * 10.0f;
    const float m0 = xb[3] * r0, m1 = xb[4] * r1, m2 = xb[5] * r2;
    const float s0 = xb[6] * r0, s1 = xb[7] * r1, s2 = xb[8] * r2;

    if (tid == 0) s_cnt = 0;
    for (int j = tid * 4; j < RIR_LEN; j += BLOCK * 4)
        *(float4*)&s_tile[j] = make_float4(0.f, 0.f, 0.f, 0.f);
    __syncthreads();

    if (mode >= 1) {
        // one candidate per thread: r = sl + tid*NSL  (covers all r<NTRIP)
        int r = sl + tid * NSL;
        if (r < NTRIP) {
            int mi = r / (NM * NM);
            int rem = r - mi * (NM * NM);
            int mj = rem / NM;
            int mk = rem - mj * NM;

            float si, oi_; int qi; axis_entry(mi, si, oi_, qi);
            float sj, oj_; int qj; axis_entry(mj, sj, oj_, qj);
            float sk, ok_; int qk; axis_entry(mk, sk, ok_, qk);
            int q = qi + qj + qk;
            if (q <= 10) {
                float dx = si * s0 + oi_ * r0 - m0;
                float dy = sj * s1 + oj_ * r1 - m1;
                float dz = sk * s2 + ok_ * r2 - m2;
                float dist = sqrtf(dx * dx + dy * dy + dz * dz);

                float tau = SRf * dist / CSOUND;
                float i0f = floorf(tau);
                int i0 = (int)i0f;
                if (i0 + HALFT + 1 < RIR_LEN) {  // at least one in-range tap
                    float fr = tau - i0f;
                    float amp = c_beta[q] / (4.0f * PIF * dist);
                    int slot = atomicAdd(&s_cnt, 1);
                    float4 e;
                    e.x = amp;
                    e.y = fr;
                    e.z = amp * __sinf(PIF * fr) * (1.0f / PIF);
                    e.w = __int_as_float(i0);
                    s_e[slot] = e;
                }
            }
        }
        __syncthreads();
    }

    if (mode >= 2) {
        // paint: tap ki=0 provably contributes 0, loop ki=1..80 branch-light
        const int n = s_cnt;
        const int total = n * (TAPS - 1);
        for (int w = tid; w < total; w += BLOCK) {
            int img = w / (TAPS - 1);
            int ki = w - img * (TAPS - 1) + 1;  // 1..80
            float4 e = s_e[img];
            int idx = __float_as_int(e.w) + HALFT + ki;
            if (idx >= RIR_LEN) continue;

            float tt = (float)(ki - HALFT) - e.y;  // in (-40, 40]
            float win = 0.5f * (1.0f + __cosf(PIF * (1.0f / 41.0f) * tt));
            float v = ((ki & 1) ? e.z : -e.z) * __builtin_amdgcn_rcpf(tt);
            v = (tt == 0.0f) ? e.x : v;  // integer-delay case
            atomicAdd(&s_tile[idx], v * win);
        }
        __syncthreads();
    }

    // stream partial RIR to workspace (coalesced float4)
    float* wb = ws + (size_t)(b * NSL + sl) * RIR_LEN;
    for (int j = tid * 4; j < RIR_LEN; j += BLOCK * 4)
        *(float4*)&wb[j] = *(const float4*)&s_tile[j];
}

// reduce the NSL partials per batch -> out; fold in the 8 origins
__global__ __launch_bounds__(256) void k_reduce(const float* __restrict__ x,
                                                const float* __restrict__ ws,
                                                float* __restrict__ out) {
    int t4 = (blockIdx.x * 256 + threadIdx.x) * 4;
    if (t4 < NB * RIR_LEN) {
        int b = t4 / RIR_LEN;
        int j = t4 - b * RIR_LEN;
        const float* base = ws + (size_t)b * NSL * RIR_LEN + j;
        float4 acc = *(const float4*)base;
        #pragma unroll
        for (int s = 1; s < NSL; ++s) {
            float4 v = *(const float4*)(base + (size_t)s * RIR_LEN);
            acc.x += v.x; acc.y += v.y; acc.z += v.z; acc.w += v.w;
        }
        *(float4*)(out + t4) = acc;
    }
    if (blockIdx.x == 0 && threadIdx.x < NB) {
        const float* xb = x + threadIdx.x * 9;
        float r0 = xb[0] * 10.0f, r1 = xb[1] * 10.0f, r2 = xb[2] * 10.0f;
        float d0 = (xb[3] - xb[6]) * r0;
        float d1 = (xb[4] - xb[7]) * r1;
        float d2 = (xb[5] - xb[8]) * r2;
        float dist = sqrtf(d0 * d0 + d1 * d1 + d2 * d2);
        out[NB * RIR_LEN + threadIdx.x] = 40.0f + SRf * dist / CSOUND;
    }
}

extern "C" void kernel_launch(void* const* d_in, const int* in_sizes, int n_in,
                              void* d_out, int out_size, void* d_ws, size_t ws_size,
                              hipStream_t stream) {
    const float* x = (const float*)d_in[0];
    float* out = (float*)d_out;
    float* ws = (float*)d_ws;  // NB*NSL*RIR_LEN floats = 24.6 MB

    // --- instrumentation: phase-ablation dispatches (rocprof times each) ---
    k_paint<<<NB * NSL, BLOCK, 0, stream>>>(x, ws, 0);  // zero + write
    k_paint<<<NB * NSL, BLOCK, 0, stream>>>(x, ws, 1);  // + scan
    // --- real pipeline: full paint, then reduce ---
    k_paint<<<NB * NSL, BLOCK, 0, stream>>>(x, ws, 2);  // + paint (authoritative ws)
    int rblocks = (NB * RIR_LEN / 4 + 255) / 256;  // 188
    k_reduce<<<rblocks, 256, 0, stream>>>(x, ws, out);
}

// Round 10
// 26.386 us; speedup vs baseline: 6.8466x; 1.5178x over previous
//
#include <hip/hip_runtime.h>
#include <math.h>

#define SRf 48000.0f
#define CSOUND 343.0f
#define RIR_LEN 24000
#define TAPS 81
#define HALFT 40
#define NB 8
#define NM 21                 // per-axis entries with order <= 10
#define NTRIP (NM * NM * NM)  // 9261 candidate triples
#define NSL 16                // image-slices per batch (r % NSL) -> 128 balanced blocks
#define BLOCK 1024
#define CAPS 256              // per-slice keeper capacity (mean ~98)

// 0.9^q for q = 0..10
__device__ __constant__ float c_beta[11] = {
    1.0f, 0.9f, 0.81f, 0.729f, 0.6561f, 0.59049f, 0.531441f,
    0.4782969f, 0.43046721f, 0.387420489f, 0.3486784401f};

// Per-axis image table restricted to order <= 10 (pure arithmetic):
//   m in [0,10]:  p=0, n=m-5  -> sign=+1, off=2n, order=2|n|
//   m in [11,20]: p=1, n=m-15 -> sign=-1, off=2n, order=|n-1|+|n|
__device__ __forceinline__ void axis_entry(int m, float& sgn, float& off, int& ord) {
    if (m < 11) {
        int n = m - 5;
        sgn = 1.0f;
        off = 2.0f * (float)n;
        ord = 2 * abs(n);
    } else {
        int n = m - 15;
        sgn = -1.0f;
        off = 2.0f * (float)n;
        ord = abs(n - 1) + abs(n);
    }
}

// kernel 1: block = (batch, slice). Scan residue class r%NSL==sl register-only,
// compact keepers to LDS, paint private 96 KB LDS RIR, stream to ws.
// Per-block work is input-independent -> perfectly balanced.
__global__ __launch_bounds__(BLOCK) void k_paint(const float* __restrict__ x,
                                                 float* __restrict__ ws) {
    __shared__ __align__(16) float s_tile[RIR_LEN];  // 96 KB private partial RIR
    __shared__ float4 s_e[CAPS];  // {amp, frac, amp*sin(pi*frac)/pi, i0}
    __shared__ int s_cnt;

    const float PIF = 3.14159265358979323846f;
    const int b = blockIdx.x >> 4;          // / NSL
    const int sl = blockIdx.x & (NSL - 1);
    const int tid = threadIdx.x;

    const float* xb = x + b * 9;
    const float r0 = xb[0] * 10.0f, r1 = xb[1] * 10.0f, r2 = xb[2] * 10.0f;
    const float m0 = xb[3] * r0, m1 = xb[4] * r1, m2 = xb[5] * r2;
    const float s0 = xb[6] * r0, s1 = xb[7] * r1, s2 = xb[8] * r2;

    if (tid == 0) s_cnt = 0;
    for (int j = tid * 4; j < RIR_LEN; j += BLOCK * 4)
        *(float4*)&s_tile[j] = make_float4(0.f, 0.f, 0.f, 0.f);
    __syncthreads();

    // ---- phase A: register-only scan of residue class (one candidate/thread)
    {
        int r = sl + tid * NSL;
        if (r < NTRIP) {
            int mi = r / (NM * NM);
            int rem = r - mi * (NM * NM);
            int mj = rem / NM;
            int mk = rem - mj * NM;

            float si, oi_; int qi; axis_entry(mi, si, oi_, qi);
            float sj, oj_; int qj; axis_entry(mj, sj, oj_, qj);
            float sk, ok_; int qk; axis_entry(mk, sk, ok_, qk);
            int q = qi + qj + qk;
            if (q <= 10) {
                float dx = si * s0 + oi_ * r0 - m0;
                float dy = sj * s1 + oj_ * r1 - m1;
                float dz = sk * s2 + ok_ * r2 - m2;
                float dist = sqrtf(dx * dx + dy * dy + dz * dz);

                float tau = SRf * dist / CSOUND;
                float i0f = floorf(tau);
                int i0 = (int)i0f;
                if (i0 + HALFT + 1 < RIR_LEN) {  // at least one in-range tap
                    float fr = tau - i0f;
                    float amp = c_beta[q] / (4.0f * PIF * dist);
                    int slot = atomicAdd(&s_cnt, 1);
                    float4 e;
                    e.x = amp;
                    e.y = fr;
                    e.z = amp * __sinf(PIF * fr) * (1.0f / PIF);
                    e.w = __int_as_float(i0);
                    s_e[slot] = e;
                }
            }
        }
    }
    __syncthreads();

    // ---- phase B: flattened (image, tap) paint. Tap ki=0 contributes exactly 0
    // (|t|>40 unless frac==0, then sinc(-40)=0), so loop ki=1..80.
    const int n = s_cnt;
    const int total = n * (TAPS - 1);
    for (int w = tid; w < total; w += BLOCK) {
        int img = w / (TAPS - 1);
        int ki = w - img * (TAPS - 1) + 1;  // 1..80
        float4 e = s_e[img];
        int idx = __float_as_int(e.w) + HALFT + ki;
        if (idx >= RIR_LEN) continue;

        float tt = (float)(ki - HALFT) - e.y;  // in (-40, 40]
        float win = 0.5f * (1.0f + __cosf(PIF * (1.0f / 41.0f) * tt));
        float v = ((ki & 1) ? e.z : -e.z) * __builtin_amdgcn_rcpf(tt);
        v = (tt == 0.0f) ? e.x : v;  // exact-integer delay
        atomicAdd(&s_tile[idx], v * win);
    }
    __syncthreads();

    // ---- phase C: stream partial RIR to workspace (coalesced float4)
    float* wb = ws + (size_t)(b * NSL + sl) * RIR_LEN;
    for (int j = tid * 4; j < RIR_LEN; j += BLOCK * 4)
        *(float4*)&wb[j] = *(const float4*)&s_tile[j];
}

// kernel 2: sum the NSL partials per batch -> out; fold in the 8 origins.
__global__ __launch_bounds__(256) void k_reduce(const float* __restrict__ x,
                                                const float* __restrict__ ws,
                                                float* __restrict__ out) {
    int t4 = (blockIdx.x * 256 + threadIdx.x) * 4;
    if (t4 < NB * RIR_LEN) {
        int b = t4 / RIR_LEN;
        int j = t4 - b * RIR_LEN;
        const float* base = ws + (size_t)b * NSL * RIR_LEN + j;
        float4 acc = *(const float4*)base;
        #pragma unroll
        for (int s = 1; s < NSL; ++s) {
            float4 v = *(const float4*)(base + (size_t)s * RIR_LEN);
            acc.x += v.x; acc.y += v.y; acc.z += v.z; acc.w += v.w;
        }
        *(float4*)(out + t4) = acc;
    }
    if (blockIdx.x == 0 && threadIdx.x < NB) {
        const float* xb = x + threadIdx.x * 9;
        float r0 = xb[0] * 10.0f, r1 = xb[1] * 10.0f, r2 = xb[2] * 10.0f;
        float d0 = (xb[3] - xb[6]) * r0;
        float d1 = (xb[4] - xb[7]) * r1;
        float d2 = (xb[5] - xb[8]) * r2;
        float dist = sqrtf(d0 * d0 + d1 * d1 + d2 * d2);
        out[NB * RIR_LEN + threadIdx.x] = 40.0f + SRf * dist / CSOUND;
    }
}

extern "C" void kernel_launch(void* const* d_in, const int* in_sizes, int n_in,
                              void* d_out, int out_size, void* d_ws, size_t ws_size,
                              hipStream_t stream) {
    const float* x = (const float*)d_in[0];
    float* out = (float*)d_out;
    float* ws = (float*)d_ws;  // NB*NSL*RIR_LEN floats = 12.3 MB

    k_paint<<<NB * NSL, BLOCK, 0, stream>>>(x, ws);
    int rblocks = (NB * RIR_LEN / 4 + 255) / 256;  // 188
    k_reduce<<<rblocks, 256, 0, stream>>>(x, ws, out);
}